// Round 10
// baseline (730.844 us; speedup 1.0000x reference)
//
#include <hip/hip_runtime.h>
#include <math.h>

#define N_NODES 50000
#define N_EDGES 800000
#define E_TOT   850000
#define F_IN    256
#define F1      512
#define HID     128
#define HEADS   4
#define F_OUT   64

typedef __attribute__((ext_vector_type(8))) short short8;
typedef __attribute__((ext_vector_type(4))) float f32x4;
typedef unsigned short ushort_t;
typedef unsigned int uint_t;

__device__ __forceinline__ float lrelu(float x){ return x > 0.f ? x : 0.2f*x; }
__device__ __forceinline__ float elu(float x){ return x > 0.f ? x : expm1f(x); }

__device__ __forceinline__ ushort_t f2b(float f){
  uint_t u = __builtin_bit_cast(uint_t, f);
  u += 0x7fffu + ((u >> 16) & 1u);
  return (ushort_t)(u >> 16);
}
__device__ __forceinline__ float blo(uint_t u){ return __builtin_bit_cast(float, u << 16); }
__device__ __forceinline__ float bhi(uint_t u){ return __builtin_bit_cast(float, u & 0xffff0000u); }
__device__ __forceinline__ float b2f(ushort_t s){ return __builtin_bit_cast(float, (uint_t)s << 16); }

// ---------------- CSR build ----------------
__global__ void hist_kernel(const int* __restrict__ ei, int* __restrict__ deg){
  int e = blockIdx.x*blockDim.x + threadIdx.x;
  if (e >= E_TOT) return;
  int dst = (e < N_EDGES) ? ei[N_EDGES + e] : (e - N_EDGES);
  atomicAdd(&deg[dst], 1);
}

__global__ __launch_bounds__(256) void scan1_kernel(const int* __restrict__ deg,
                                                    int* __restrict__ offs,
                                                    int* __restrict__ bsum){
  __shared__ int sd[256];
  const int tid = threadIdx.x;
  const int i = blockIdx.x*256 + tid;
  int v = (i < N_NODES) ? deg[i] : 0;
  sd[tid] = v; __syncthreads();
  #pragma unroll
  for (int off = 1; off < 256; off <<= 1){
    int t = (tid >= off) ? sd[tid - off] : 0;
    __syncthreads();
    sd[tid] += t;
    __syncthreads();
  }
  if (i < N_NODES) offs[i] = sd[tid] - v;   // block-local exclusive
  if (tid == 255) bsum[blockIdx.x] = sd[255];
}

__global__ __launch_bounds__(256) void scan2_kernel(const int* __restrict__ bsum,
                                                    int* __restrict__ bbase, int nb){
  __shared__ int sd[256];
  const int tid = threadIdx.x;
  int v = (tid < nb) ? bsum[tid] : 0;
  sd[tid] = v; __syncthreads();
  #pragma unroll
  for (int off = 1; off < 256; off <<= 1){
    int t = (tid >= off) ? sd[tid - off] : 0;
    __syncthreads();
    sd[tid] += t;
    __syncthreads();
  }
  if (tid < nb) bbase[tid] = sd[tid] - v;
}

__global__ __launch_bounds__(256) void scan3_kernel(int* __restrict__ offs,
                                                    const int* __restrict__ bbase,
                                                    int* __restrict__ cur){
  const int i = blockIdx.x*256 + threadIdx.x;
  if (i < N_NODES){
    int o = offs[i] + bbase[blockIdx.x];
    offs[i] = o;
    cur[i] = o;
  }
  if (blockIdx.x == 0 && threadIdx.x == 0) offs[N_NODES] = E_TOT;
}

__global__ void scatter_kernel(const int* __restrict__ ei, int* __restrict__ cur,
                               int* __restrict__ ssrc){
  int e = blockIdx.x*blockDim.x + threadIdx.x;
  if (e >= E_TOT) return;
  int src, dst;
  if (e < N_EDGES){ src = ei[e]; dst = ei[N_EDGES + e]; }
  else            { src = e - N_EDGES; dst = src; }
  int pos = atomicAdd(&cur[dst], 1);
  ssrc[pos] = src;
}

// ---------------- degree-bucket counting sort (descending) ----------------
// perm groups dsts of equal degree so agg1s waves (8 dsts each) have uniform
// chunk counts -> no exec-mask divergence; heavy blocks launch first (tail).
__global__ __launch_bounds__(256) void dhist_kernel(const int* __restrict__ deg,
                                                    int* __restrict__ dhist){
  const int i = blockIdx.x*256 + threadIdx.x;
  if (i < N_NODES){
    const int b = 127 - min(deg[i], 127);      // descending degree
    atomicAdd(&dhist[b], 1);
  }
}

__global__ __launch_bounds__(128) void dscan_kernel(const int* __restrict__ dhist,
                                                    int* __restrict__ dcur){
  __shared__ int sd[128];
  const int tid = threadIdx.x;
  int v = dhist[tid];
  sd[tid] = v; __syncthreads();
  #pragma unroll
  for (int off = 1; off < 128; off <<= 1){
    int t = (tid >= off) ? sd[tid - off] : 0;
    __syncthreads();
    sd[tid] += t;
    __syncthreads();
  }
  dcur[tid] = sd[tid] - v;                     // exclusive base per bucket
}

__global__ __launch_bounds__(256) void dscatter_kernel(const int* __restrict__ deg,
                                                       int* __restrict__ dcur,
                                                       int* __restrict__ perm){
  const int i = blockIdx.x*256 + threadIdx.x;
  if (i < N_NODES){
    const int b = 127 - min(deg[i], 127);
    const int pos = atomicAdd(&dcur[b], 1);
    perm[pos] = i;
  }
}

// ---------------- prep: fp32 -> bf16 ----------------
__global__ __launch_bounds__(256) void cvt_x_kernel(const float* __restrict__ x,
                                                    ushort_t* __restrict__ xb){
  const int t = blockIdx.x*256 + threadIdx.x;     // 8 elems/thread
  const float4 a = ((const float4*)x)[t*2];
  const float4 b = ((const float4*)x)[t*2 + 1];
  uint4 o;
  o.x = (uint_t)f2b(a.x) | ((uint_t)f2b(a.y) << 16);
  o.y = (uint_t)f2b(a.z) | ((uint_t)f2b(a.w) << 16);
  o.z = (uint_t)f2b(b.x) | ((uint_t)f2b(b.y) << 16);
  o.w = (uint_t)f2b(b.z) | ((uint_t)f2b(b.w) << 16);
  ((uint4*)xb)[t] = o;
}

// W [K][N] fp32 -> Wt [N][K] bf16   (K,N multiples of 64)
__global__ __launch_bounds__(256) void transpose_bf16_kernel(const float* __restrict__ W,
                                                             ushort_t* __restrict__ Wt,
                                                             int K, int N){
  __shared__ float tile[64][65];
  const int k0 = blockIdx.x*64, n0 = blockIdx.y*64;
  const int c = threadIdx.x & 63, r4 = threadIdx.x >> 6;
  for (int r = r4; r < 64; r += 4)
    tile[r][c] = W[(size_t)(k0 + r)*N + n0 + c];
  __syncthreads();
  for (int r = r4; r < 64; r += 4)
    Wt[(size_t)(n0 + r)*K + k0 + c] = f2b(tile[c][r]);
}

// ---------------- bf16 MFMA GEMM: C[M,N] = A[M,K] @ Bt[N,K]^T ----------------
template<int K, int WR, int WC>
__global__ __launch_bounds__(256) void gemm_bf16(const ushort_t* __restrict__ A,
                                                 const ushort_t* __restrict__ Bt,
                                                 ushort_t* __restrict__ C,
                                                 int M, int N){
  constexpr int BM = WR*64, BN = WC*64, BKP = 40;  // pad 32->40 (80B rows, 16B aligned)
  __shared__ ushort_t As[BM*BKP];
  __shared__ ushort_t Bs[BN*BKP];
  const int tid = threadIdx.x;
  const int wave = tid >> 6, lane = tid & 63, quad = lane >> 4, l16 = lane & 15;
  const int wm = wave % WR, wn = wave / WR;
  const int m0 = blockIdx.x*BM, n0 = blockIdx.y*BN;
  f32x4 acc[4][4] = {};
  for (int k0 = 0; k0 < K; k0 += 32){
    #pragma unroll
    for (int s = tid; s < BM*4; s += 256){
      int r = s >> 2, c = s & 3;
      int gr = m0 + r; if (gr >= M) gr = M - 1;
      *(uint4*)(As + r*BKP + c*8) = *(const uint4*)(A + (size_t)gr*K + k0 + c*8);
    }
    #pragma unroll
    for (int s = tid; s < BN*4; s += 256){
      int r = s >> 2, c = s & 3;
      *(uint4*)(Bs + r*BKP + c*8) = *(const uint4*)(Bt + (size_t)(n0 + r)*K + k0 + c*8);
    }
    __syncthreads();
    short8 af[4], bfr[4];
    #pragma unroll
    for (int i = 0; i < 4; ++i)
      af[i] = *(const short8*)(As + (wm*64 + i*16 + l16)*BKP + quad*8);
    #pragma unroll
    for (int j = 0; j < 4; ++j)
      bfr[j] = *(const short8*)(Bs + (wn*64 + j*16 + l16)*BKP + quad*8);
    #pragma unroll
    for (int i = 0; i < 4; ++i)
      #pragma unroll
      for (int j = 0; j < 4; ++j)
        acc[i][j] = __builtin_amdgcn_mfma_f32_16x16x32_bf16(af[i], bfr[j], acc[i][j], 0, 0, 0);
    __syncthreads();
  }
  #pragma unroll
  for (int i = 0; i < 4; ++i){
    #pragma unroll
    for (int r = 0; r < 4; ++r){
      int row = m0 + wm*64 + i*16 + quad*4 + r;
      if (row < M){
        #pragma unroll
        for (int j = 0; j < 4; ++j){
          int col = n0 + wn*64 + j*16 + l16;
          C[(size_t)row*N + col] = f2b(acc[i][j][r]);
        }
      }
    }
  }
}

// ---------------- layer-1 logits from bf16 h1 ----------------
__global__ __launch_bounds__(128) void logits1_kernel(const ushort_t* __restrict__ h1b,
                                                      const float* __restrict__ a_src,
                                                      const float* __restrict__ a_dst,
                                                      float* __restrict__ als,
                                                      float* __restrict__ ald){
  const int n = blockIdx.x;
  const int tid = threadIdx.x;
  const int head = tid >> 5, p = tid & 31;
  const uint2 v = *(const uint2*)(h1b + (size_t)n*F1 + tid*4);
  float h0 = blo(v.x), h1 = bhi(v.x), h2 = blo(v.y), h3 = bhi(v.y);
  const float4 as = *(const float4*)(a_src + head*HID + p*4);
  const float4 ad = *(const float4*)(a_dst + head*HID + p*4);
  float ds = h0*as.x + h1*as.y + h2*as.z + h3*as.w;
  float dd = h0*ad.x + h1*ad.y + h2*ad.z + h3*ad.w;
  #pragma unroll
  for (int off = 16; off >= 1; off >>= 1){
    ds += __shfl_down(ds, off, 32);
    dd += __shfl_down(dd, off, 32);
  }
  if (p == 0){ als[n*4 + head] = ds; ald[n*4 + head] = dd; }
}

#define FMA8(hv, al) do{ \
  acc[0] = fmaf(blo((hv).x), (al), acc[0]); \
  acc[1] = fmaf(bhi((hv).x), (al), acc[1]); \
  acc[2] = fmaf(blo((hv).y), (al), acc[2]); \
  acc[3] = fmaf(bhi((hv).y), (al), acc[3]); \
  acc[4] = fmaf(blo((hv).z), (al), acc[4]); \
  acc[5] = fmaf(bhi((hv).z), (al), acc[5]); \
  acc[6] = fmaf(blo((hv).w), (al), acc[6]); \
  acc[7] = fmaf(bhi((hv).w), (al), acc[7]); }while(0)

// ---------------- layer-1 aggregation: XCD-sliced, 8-lane group per dst ----
// slice s = blockIdx.x & 7 -> XCD s (keeps the 427->241 MB FETCH cut).
// Wave = 8 dsts via perm (degree-sorted: uniform chunk count per wave).
__global__ __launch_bounds__(256) void agg1s_kernel(const ushort_t* __restrict__ h1b,
                                                    const float* __restrict__ als,
                                                    const float* __restrict__ ald1,
                                                    const float* __restrict__ b1,
                                                    const int* __restrict__ offs,
                                                    const int* __restrict__ ssrc,
                                                    const int* __restrict__ perm,
                                                    ushort_t* __restrict__ hb){
  __shared__ int   shsrc[4][8][8];
  __shared__ float shal[4][8][8];
  const int wave = threadIdx.x >> 6, lane = threadIdx.x & 63;
  const int s = blockIdx.x & 7;            // feature slice == XCD
  const int gblk = blockIdx.x >> 3;        // dst-group block (32 dsts)
  const int head = s >> 1;
  const int g  = lane >> 3;                // group within wave (0..7)
  const int l8 = lane & 7;                 // lane within group
  const int pidx = gblk*32 + wave*8 + g;
  const bool valid = pidx < N_NODES;
  const int n = valid ? perm[pidx] : 0;

  const int s0  = valid ? offs[n]     : 0;
  const int s1v = valid ? offs[n + 1] : 0;
  const int nE  = s1v - s0;
  const float aldv = valid ? ald1[n*4 + head] : 0.f;

  const ushort_t* hcol = h1b + s*64 + l8*8;
  float acc[8] = {0.f,0.f,0.f,0.f,0.f,0.f,0.f,0.f};
  float dsum = 0.f;

  const int nC = (nE + 7) >> 3;
  for (int c = 0; c < nC; ++c){
    const int idx = s0 + c*8 + l8;
    int sc = 0; float a = 0.f;
    if (idx < s1v){
      sc = ssrc[idx];
      a  = __expf(lrelu(als[sc*4 + head] + aldv));
    }
    shsrc[wave][g][l8] = sc;
    shal[wave][g][l8]  = a;
    dsum += a;                             // each lane sums the alphas IT staged
    #pragma unroll
    for (int k = 0; k < 8; ++k){
      const int scb  = shsrc[wave][g][k];
      const float al = shal[wave][g][k];
      const uint4 v = *(const uint4*)(hcol + ((size_t)scb << 9));
      FMA8(v, al);
    }
  }

  // 3-shuffle within-group denominator reduce (group = aligned 8 lanes)
  dsum += __shfl_xor(dsum, 1);
  dsum += __shfl_xor(dsum, 2);
  dsum += __shfl_xor(dsum, 4);

  if (valid){
    const float rd = 1.0f / (dsum + 1e-16f);
    const float4 ba = *(const float4*)(b1 + s*64 + l8*8);
    const float4 bb = *(const float4*)(b1 + s*64 + l8*8 + 4);
    float o0 = elu(fmaf(acc[0], rd, ba.x)), o1 = elu(fmaf(acc[1], rd, ba.y));
    float o2 = elu(fmaf(acc[2], rd, ba.z)), o3 = elu(fmaf(acc[3], rd, ba.w));
    float o4 = elu(fmaf(acc[4], rd, bb.x)), o5 = elu(fmaf(acc[5], rd, bb.y));
    float o6 = elu(fmaf(acc[6], rd, bb.z)), o7 = elu(fmaf(acc[7], rd, bb.w));
    uint4 o;
    o.x = (uint_t)f2b(o0) | ((uint_t)f2b(o1) << 16);
    o.y = (uint_t)f2b(o2) | ((uint_t)f2b(o3) << 16);
    o.z = (uint_t)f2b(o4) | ((uint_t)f2b(o5) << 16);
    o.w = (uint_t)f2b(o6) | ((uint_t)f2b(o7) << 16);
    *(uint4*)(hb + (size_t)n*F1 + s*64 + l8*8) = o;
  }
}

// ---------------- layer-2 logits from bf16 g ----------------
__global__ __launch_bounds__(64) void logits2_kernel(const ushort_t* __restrict__ gb,
                                                     const float* __restrict__ a_src,
                                                     const float* __restrict__ a_dst,
                                                     float* __restrict__ als,
                                                     float* __restrict__ ald){
  const int n = blockIdx.x;
  const int tid = threadIdx.x;
  const float v = b2f(gb[(size_t)n*F_OUT + tid]);
  float ds = v * a_src[tid];
  float dd = v * a_dst[tid];
  #pragma unroll
  for (int off = 32; off >= 1; off >>= 1){
    ds += __shfl_xor(ds, off);
    dd += __shfl_xor(dd, off);
  }
  if (tid == 0){ als[n] = ds; ald[n] = dd; }
}

// ---------------- layer-2 aggregation (wave per dst) ----------------
__global__ __launch_bounds__(256) void agg2_kernel(const ushort_t* __restrict__ gb,
                                                   const float* __restrict__ als,
                                                   const float* __restrict__ ald2,
                                                   const float* __restrict__ b2,
                                                   const int* __restrict__ offs,
                                                   const int* __restrict__ ssrc,
                                                   float* __restrict__ out){
  __shared__ int   shsrc[4][64];
  __shared__ float shal[4][64];
  const int wave = threadIdx.x >> 6, lane = threadIdx.x & 63;
  const int n = blockIdx.x*4 + wave;
  const float ald = ald2[n];
  const int s0 = offs[n], s1 = offs[n+1];
  const int nE = s1 - s0;

  if (nE <= 64){
    float av = 0.f; int sc = 0;
    if (lane < nE){
      sc = ssrc[s0 + lane];
      av = __expf(lrelu(als[sc] + ald));
    }
    shsrc[wave][lane] = sc;
    shal[wave][lane] = av;

    const ushort_t* gbase = gb + lane;
    const int nE4 = (nE + 3) & ~3;
    float acc = 0.f, dsum = 0.f;

    ushort_t v0 = gbase[(size_t)shsrc[wave][0] << 6];
    ushort_t v1 = gbase[(size_t)shsrc[wave][1] << 6];
    ushort_t v2 = gbase[(size_t)shsrc[wave][2] << 6];
    ushort_t v3 = gbase[(size_t)shsrc[wave][3] << 6];
    float al0 = shal[wave][0];
    float al1 = shal[wave][1];
    float al2 = shal[wave][2];
    float al3 = shal[wave][3];
    for (int k = 0; k < nE4; k += 4){
      ushort_t p0 = v0, p1 = v1, p2 = v2, p3 = v3;
      float q0 = 0.f, q1 = 0.f, q2 = 0.f, q3 = 0.f;
      if (k + 4 < nE4){
        p0 = gbase[(size_t)shsrc[wave][k+4] << 6];
        p1 = gbase[(size_t)shsrc[wave][k+5] << 6];
        p2 = gbase[(size_t)shsrc[wave][k+6] << 6];
        p3 = gbase[(size_t)shsrc[wave][k+7] << 6];
        q0 = shal[wave][k+4];
        q1 = shal[wave][k+5];
        q2 = shal[wave][k+6];
        q3 = shal[wave][k+7];
      }
      dsum += (al0 + al1) + (al2 + al3);
      acc = fmaf(b2f(v0), al0, acc);
      acc = fmaf(b2f(v1), al1, acc);
      acc = fmaf(b2f(v2), al2, acc);
      acc = fmaf(b2f(v3), al3, acc);
      v0 = p0; v1 = p1; v2 = p2; v3 = p3;
      al0 = q0; al1 = q1; al2 = q2; al3 = q3;
    }
    const float rd = 1.0f / (dsum + 1e-16f);
    out[(size_t)n*F_OUT + lane] = fmaf(acc, rd, b2[lane]);
    return;
  }

  // ---- fallback (deg > 64): original two-pass path ----
  float dsum = 0.f;
  for (int e = s0 + lane; e < s1; e += 64)
    dsum += __expf(lrelu(als[ssrc[e]] + ald));
  #pragma unroll
  for (int off = 32; off >= 1; off >>= 1)
    dsum += __shfl_xor(dsum, off);
  const float rd = 1.0f / (dsum + 1e-16f);

  float acc = 0.f;
  for (int ce = s0; ce < s1; ce += 64){
    const int idx = ce + lane;
    if (idx < s1){
      const int sc = ssrc[idx];
      shsrc[wave][lane] = sc;
      shal[wave][lane] = __expf(lrelu(als[sc] + ald)) * rd;
    }
    const int nB = min(64, s1 - ce);
    for (int k = 0; k < nB; ++k){
      const int scb = shsrc[wave][k];
      const float al = shal[wave][k];
      acc = fmaf(b2f(gb[(size_t)scb*F_OUT + lane]), al, acc);
    }
  }
  out[(size_t)n*F_OUT + lane] = acc + b2[lane];
}

#undef FMA8

extern "C" void kernel_launch(void* const* d_in, const int* in_sizes, int n_in,
                              void* d_out, int out_size, void* d_ws, size_t ws_size,
                              hipStream_t stream){
  const float* x      = (const float*)d_in[0];
  const int*   ei     = (const int*)  d_in[1];
  const float* W1     = (const float*)d_in[2];
  const float* a_src1 = (const float*)d_in[3];
  const float* a_dst1 = (const float*)d_in[4];
  const float* b1     = (const float*)d_in[5];
  const float* W2     = (const float*)d_in[6];
  const float* a_src2 = (const float*)d_in[7];
  const float* a_dst2 = (const float*)d_in[8];
  const float* b2     = (const float*)d_in[9];
  float* out = (float*)d_out;

  char* ws = (char*)d_ws;
  ushort_t* h1b  = (ushort_t*)(ws + 0UL);            // [N,512] bf16 = 51.2 MB
  ushort_t* hb   = (ushort_t*)(ws + 51200000UL);     // [N,512] bf16 = 51.2 MB
  ushort_t* xb   = (ushort_t*)(ws + 102400000UL);    // [N,256] bf16 = 25.6 MB
  ushort_t* gb   = (ushort_t*)(ws + 128000000UL);    // [N,64]  bf16 = 6.4 MB
  ushort_t* W1t  = (ushort_t*)(ws + 134400000UL);    // [512][256] bf16
  ushort_t* W2t  = (ushort_t*)(ws + 134662144UL);    // [64][512] bf16
  float*    als1 = (float*)   (ws + 134727680UL);    // [N,4]
  float*    ald1 = (float*)   (ws + 135527680UL);    // [N,4]
  float*    als2 = (float*)   (ws + 136327680UL);    // [N]  (aliases perm; logits2 runs after agg1s)
  float*    ald2 = (float*)   (ws + 136527680UL);    // [N]
  int*      deg  = (int*)     (ws + 136727680UL);    // [N]
  int*      offs = (int*)     (ws + 136927680UL);    // [N+1]
  int*      bsum = (int*)     (ws + 137127744UL);    // [196]
  int*      bbase= (int*)     (ws + 137128544UL);    // [196]
  int*      cur  = (int*)     (ws + 137129600UL);    // [N]
  int*      ssrc = (int*)     (ws + 137329600UL);    // [E_TOT] = 3.4 MB

  // degree-sort scratch: perm aliases als2 (dead until logits2);
  // dhist/dcur alias bsum/bbase (dead after scan3)
  int*      perm  = (int*)    (ws + 136327680UL);    // [N]
  int*      dhist = (int*)    (ws + 137127744UL);    // [128]
  int*      dcur  = (int*)    (ws + 137128544UL);    // [128]

  hipMemsetAsync(deg, 0, 200000, stream);

  const int eb = (E_TOT + 255) / 256;
  const int nb = (N_NODES + 255) / 256;              // 196
  hist_kernel   <<<eb, 256, 0, stream>>>(ei, deg);
  scan1_kernel  <<<nb, 256, 0, stream>>>(deg, offs, bsum);
  scan2_kernel  <<<1, 256, 0, stream>>>(bsum, bbase, nb);
  scan3_kernel  <<<nb, 256, 0, stream>>>(offs, bbase, cur);
  scatter_kernel<<<eb, 256, 0, stream>>>(ei, cur, ssrc);

  // degree-bucket counting sort (after scans: bsum/bbase now dead)
  hipMemsetAsync(dhist, 0, 512, stream);
  dhist_kernel   <<<nb, 256, 0, stream>>>(deg, dhist);
  dscan_kernel   <<<1, 128, 0, stream>>>(dhist, dcur);
  dscatter_kernel<<<nb, 256, 0, stream>>>(deg, dcur, perm);

  cvt_x_kernel        <<<6250, 256, 0, stream>>>(x, xb);
  transpose_bf16_kernel<<<dim3(4, 8), 256, 0, stream>>>(W1, W1t, F_IN, F1);
  transpose_bf16_kernel<<<dim3(8, 1), 256, 0, stream>>>(W2, W2t, F1, F_OUT);

  gemm_bf16<F_IN, 2, 2><<<dim3(391, 4), 256, 0, stream>>>(xb, W1t, h1b, N_NODES, F1);
  logits1_kernel<<<N_NODES, 128, 0, stream>>>(h1b, a_src1, a_dst1, als1, ald1);
  // 1563 dst-blocks (32 dsts each) x 8 feature slices; slice = blockIdx & 7
  agg1s_kernel  <<<12504, 256, 0, stream>>>(h1b, als1, ald1, b1, offs, ssrc, perm, hb);

  gemm_bf16<F1, 4, 1><<<dim3(196, 1), 256, 0, stream>>>(hb, W2t, gb, N_NODES, F_OUT);
  logits2_kernel<<<N_NODES, 64, 0, stream>>>(gb, a_src2, a_dst2, als2, ald2);
  agg2_kernel   <<<12500, 256, 0, stream>>>(gb, als2, ald2, b2, offs, ssrc, out);
}

// Round 11
// 474.149 us; speedup vs baseline: 1.5414x; 1.5414x over previous
//
#include <hip/hip_runtime.h>
#include <math.h>

#define N_NODES 50000
#define N_EDGES 800000
#define E_TOT   850000
#define F_IN    256
#define F1      512
#define HID     128
#define HEADS   4
#define F_OUT   64

typedef __attribute__((ext_vector_type(8))) short short8;
typedef __attribute__((ext_vector_type(4))) float f32x4;
typedef unsigned short ushort_t;
typedef unsigned int uint_t;

__device__ __forceinline__ float lrelu(float x){ return x > 0.f ? x : 0.2f*x; }
__device__ __forceinline__ float elu(float x){ return x > 0.f ? x : expm1f(x); }

__device__ __forceinline__ ushort_t f2b(float f){
  uint_t u = __builtin_bit_cast(uint_t, f);
  u += 0x7fffu + ((u >> 16) & 1u);
  return (ushort_t)(u >> 16);
}
__device__ __forceinline__ float blo(uint_t u){ return __builtin_bit_cast(float, u << 16); }
__device__ __forceinline__ float bhi(uint_t u){ return __builtin_bit_cast(float, u & 0xffff0000u); }
__device__ __forceinline__ float b2f(ushort_t s){ return __builtin_bit_cast(float, (uint_t)s << 16); }

// ---------------- CSR build ----------------
__global__ void hist_kernel(const int* __restrict__ ei, int* __restrict__ deg){
  int e = blockIdx.x*blockDim.x + threadIdx.x;
  if (e >= E_TOT) return;
  int dst = (e < N_EDGES) ? ei[N_EDGES + e] : (e - N_EDGES);
  atomicAdd(&deg[dst], 1);
}

__global__ __launch_bounds__(256) void scan1_kernel(const int* __restrict__ deg,
                                                    int* __restrict__ offs,
                                                    int* __restrict__ bsum){
  __shared__ int sd[256];
  const int tid = threadIdx.x;
  const int i = blockIdx.x*256 + tid;
  int v = (i < N_NODES) ? deg[i] : 0;
  sd[tid] = v; __syncthreads();
  #pragma unroll
  for (int off = 1; off < 256; off <<= 1){
    int t = (tid >= off) ? sd[tid - off] : 0;
    __syncthreads();
    sd[tid] += t;
    __syncthreads();
  }
  if (i < N_NODES) offs[i] = sd[tid] - v;   // block-local exclusive
  if (tid == 255) bsum[blockIdx.x] = sd[255];
}

__global__ __launch_bounds__(256) void scan2_kernel(const int* __restrict__ bsum,
                                                    int* __restrict__ bbase, int nb){
  __shared__ int sd[256];
  const int tid = threadIdx.x;
  int v = (tid < nb) ? bsum[tid] : 0;
  sd[tid] = v; __syncthreads();
  #pragma unroll
  for (int off = 1; off < 256; off <<= 1){
    int t = (tid >= off) ? sd[tid - off] : 0;
    __syncthreads();
    sd[tid] += t;
    __syncthreads();
  }
  if (tid < nb) bbase[tid] = sd[tid] - v;
}

__global__ __launch_bounds__(256) void scan3_kernel(int* __restrict__ offs,
                                                    const int* __restrict__ bbase,
                                                    int* __restrict__ cur){
  const int i = blockIdx.x*256 + threadIdx.x;
  if (i < N_NODES){
    int o = offs[i] + bbase[blockIdx.x];
    offs[i] = o;
    cur[i] = o;
  }
  if (blockIdx.x == 0 && threadIdx.x == 0) offs[N_NODES] = E_TOT;
}

__global__ void scatter_kernel(const int* __restrict__ ei, int* __restrict__ cur,
                               int* __restrict__ ssrc){
  int e = blockIdx.x*blockDim.x + threadIdx.x;
  if (e >= E_TOT) return;
  int src, dst;
  if (e < N_EDGES){ src = ei[e]; dst = ei[N_EDGES + e]; }
  else            { src = e - N_EDGES; dst = src; }
  int pos = atomicAdd(&cur[dst], 1);
  ssrc[pos] = src;
}

// ------- degree-bucket counting sort (descending), LDS-aggregated --------
// R9 lesson: 50K global atomics into 128 counters (8 cache lines) serialize
// at the L2 atomic unit (~145us/kernel). Aggregate per-block in LDS first:
// global atomic chains drop to 196 per address (~5us total).
__global__ __launch_bounds__(256) void dhist_kernel(const int* __restrict__ deg,
                                                    int* __restrict__ dhist){
  __shared__ int lh[128];
  const int tid = threadIdx.x;
  if (tid < 128) lh[tid] = 0;
  __syncthreads();
  const int i = blockIdx.x*256 + tid;
  if (i < N_NODES){
    const int b = 127 - min(deg[i], 127);      // descending degree
    atomicAdd(&lh[b], 1);
  }
  __syncthreads();
  if (tid < 128 && lh[tid] > 0) atomicAdd(&dhist[tid], lh[tid]);
}

__global__ __launch_bounds__(128) void dscan_kernel(const int* __restrict__ dhist,
                                                    int* __restrict__ dcur){
  __shared__ int sd[128];
  const int tid = threadIdx.x;
  int v = dhist[tid];
  sd[tid] = v; __syncthreads();
  #pragma unroll
  for (int off = 1; off < 128; off <<= 1){
    int t = (tid >= off) ? sd[tid - off] : 0;
    __syncthreads();
    sd[tid] += t;
    __syncthreads();
  }
  dcur[tid] = sd[tid] - v;                     // exclusive base per bucket
}

__global__ __launch_bounds__(256) void dscatter_kernel(const int* __restrict__ deg,
                                                       int* __restrict__ dcur,
                                                       int* __restrict__ perm){
  __shared__ int lh[128];
  __shared__ int lbase[128];
  const int tid = threadIdx.x;
  if (tid < 128) lh[tid] = 0;
  __syncthreads();
  const int i = blockIdx.x*256 + tid;
  int b = 0;
  const bool act = i < N_NODES;
  if (act){
    b = 127 - min(deg[i], 127);
    atomicAdd(&lh[b], 1);
  }
  __syncthreads();
  if (tid < 128){
    const int c = lh[tid];
    if (c > 0) lbase[tid] = atomicAdd(&dcur[tid], c);   // reserve block range
    lh[tid] = 0;                                        // reuse as local cursor
  }
  __syncthreads();
  if (act){
    const int pos = lbase[b] + atomicAdd(&lh[b], 1);    // LDS cursor, no L2 contention
    perm[pos] = i;
  }
}

// ---------------- prep: fp32 -> bf16 ----------------
__global__ __launch_bounds__(256) void cvt_x_kernel(const float* __restrict__ x,
                                                    ushort_t* __restrict__ xb){
  const int t = blockIdx.x*256 + threadIdx.x;     // 8 elems/thread
  const float4 a = ((const float4*)x)[t*2];
  const float4 b = ((const float4*)x)[t*2 + 1];
  uint4 o;
  o.x = (uint_t)f2b(a.x) | ((uint_t)f2b(a.y) << 16);
  o.y = (uint_t)f2b(a.z) | ((uint_t)f2b(a.w) << 16);
  o.z = (uint_t)f2b(b.x) | ((uint_t)f2b(b.y) << 16);
  o.w = (uint_t)f2b(b.z) | ((uint_t)f2b(b.w) << 16);
  ((uint4*)xb)[t] = o;
}

// W [K][N] fp32 -> Wt [N][K] bf16   (K,N multiples of 64)
__global__ __launch_bounds__(256) void transpose_bf16_kernel(const float* __restrict__ W,
                                                             ushort_t* __restrict__ Wt,
                                                             int K, int N){
  __shared__ float tile[64][65];
  const int k0 = blockIdx.x*64, n0 = blockIdx.y*64;
  const int c = threadIdx.x & 63, r4 = threadIdx.x >> 6;
  for (int r = r4; r < 64; r += 4)
    tile[r][c] = W[(size_t)(k0 + r)*N + n0 + c];
  __syncthreads();
  for (int r = r4; r < 64; r += 4)
    Wt[(size_t)(n0 + r)*K + k0 + c] = f2b(tile[c][r]);
}

// ---------------- bf16 MFMA GEMM: C[M,N] = A[M,K] @ Bt[N,K]^T ----------------
template<int K, int WR, int WC>
__global__ __launch_bounds__(256) void gemm_bf16(const ushort_t* __restrict__ A,
                                                 const ushort_t* __restrict__ Bt,
                                                 ushort_t* __restrict__ C,
                                                 int M, int N){
  constexpr int BM = WR*64, BN = WC*64, BKP = 40;  // pad 32->40 (80B rows, 16B aligned)
  __shared__ ushort_t As[BM*BKP];
  __shared__ ushort_t Bs[BN*BKP];
  const int tid = threadIdx.x;
  const int wave = tid >> 6, lane = tid & 63, quad = lane >> 4, l16 = lane & 15;
  const int wm = wave % WR, wn = wave / WR;
  const int m0 = blockIdx.x*BM, n0 = blockIdx.y*BN;
  f32x4 acc[4][4] = {};
  for (int k0 = 0; k0 < K; k0 += 32){
    #pragma unroll
    for (int s = tid; s < BM*4; s += 256){
      int r = s >> 2, c = s & 3;
      int gr = m0 + r; if (gr >= M) gr = M - 1;
      *(uint4*)(As + r*BKP + c*8) = *(const uint4*)(A + (size_t)gr*K + k0 + c*8);
    }
    #pragma unroll
    for (int s = tid; s < BN*4; s += 256){
      int r = s >> 2, c = s & 3;
      *(uint4*)(Bs + r*BKP + c*8) = *(const uint4*)(Bt + (size_t)(n0 + r)*K + k0 + c*8);
    }
    __syncthreads();
    short8 af[4], bfr[4];
    #pragma unroll
    for (int i = 0; i < 4; ++i)
      af[i] = *(const short8*)(As + (wm*64 + i*16 + l16)*BKP + quad*8);
    #pragma unroll
    for (int j = 0; j < 4; ++j)
      bfr[j] = *(const short8*)(Bs + (wn*64 + j*16 + l16)*BKP + quad*8);
    #pragma unroll
    for (int i = 0; i < 4; ++i)
      #pragma unroll
      for (int j = 0; j < 4; ++j)
        acc[i][j] = __builtin_amdgcn_mfma_f32_16x16x32_bf16(af[i], bfr[j], acc[i][j], 0, 0, 0);
    __syncthreads();
  }
  #pragma unroll
  for (int i = 0; i < 4; ++i){
    #pragma unroll
    for (int r = 0; r < 4; ++r){
      int row = m0 + wm*64 + i*16 + quad*4 + r;
      if (row < M){
        #pragma unroll
        for (int j = 0; j < 4; ++j){
          int col = n0 + wn*64 + j*16 + l16;
          C[(size_t)row*N + col] = f2b(acc[i][j][r]);
        }
      }
    }
  }
}

// ---------------- layer-1 logits from bf16 h1 ----------------
__global__ __launch_bounds__(128) void logits1_kernel(const ushort_t* __restrict__ h1b,
                                                      const float* __restrict__ a_src,
                                                      const float* __restrict__ a_dst,
                                                      float* __restrict__ als,
                                                      float* __restrict__ ald){
  const int n = blockIdx.x;
  const int tid = threadIdx.x;
  const int head = tid >> 5, p = tid & 31;
  const uint2 v = *(const uint2*)(h1b + (size_t)n*F1 + tid*4);
  float h0 = blo(v.x), h1 = bhi(v.x), h2 = blo(v.y), h3 = bhi(v.y);
  const float4 as = *(const float4*)(a_src + head*HID + p*4);
  const float4 ad = *(const float4*)(a_dst + head*HID + p*4);
  float ds = h0*as.x + h1*as.y + h2*as.z + h3*as.w;
  float dd = h0*ad.x + h1*ad.y + h2*ad.z + h3*ad.w;
  #pragma unroll
  for (int off = 16; off >= 1; off >>= 1){
    ds += __shfl_down(ds, off, 32);
    dd += __shfl_down(dd, off, 32);
  }
  if (p == 0){ als[n*4 + head] = ds; ald[n*4 + head] = dd; }
}

#define FMA8(hv, al) do{ \
  acc[0] = fmaf(blo((hv).x), (al), acc[0]); \
  acc[1] = fmaf(bhi((hv).x), (al), acc[1]); \
  acc[2] = fmaf(blo((hv).y), (al), acc[2]); \
  acc[3] = fmaf(bhi((hv).y), (al), acc[3]); \
  acc[4] = fmaf(blo((hv).z), (al), acc[4]); \
  acc[5] = fmaf(bhi((hv).z), (al), acc[5]); \
  acc[6] = fmaf(blo((hv).w), (al), acc[6]); \
  acc[7] = fmaf(bhi((hv).w), (al), acc[7]); }while(0)

// ---------------- layer-1 aggregation: XCD-sliced, 8-lane group per dst ----
// slice s = blockIdx.x & 7 -> XCD s (keeps the 427->241 MB FETCH cut).
// Wave = 8 dsts via perm (degree-sorted: uniform chunk count per wave).
__global__ __launch_bounds__(256) void agg1s_kernel(const ushort_t* __restrict__ h1b,
                                                    const float* __restrict__ als,
                                                    const float* __restrict__ ald1,
                                                    const float* __restrict__ b1,
                                                    const int* __restrict__ offs,
                                                    const int* __restrict__ ssrc,
                                                    const int* __restrict__ perm,
                                                    ushort_t* __restrict__ hb){
  __shared__ int   shsrc[4][8][8];
  __shared__ float shal[4][8][8];
  const int wave = threadIdx.x >> 6, lane = threadIdx.x & 63;
  const int s = blockIdx.x & 7;            // feature slice == XCD
  const int gblk = blockIdx.x >> 3;        // dst-group block (32 dsts)
  const int head = s >> 1;
  const int g  = lane >> 3;                // group within wave (0..7)
  const int l8 = lane & 7;                 // lane within group
  const int pidx = gblk*32 + wave*8 + g;
  const bool valid = pidx < N_NODES;
  const int n = valid ? perm[pidx] : 0;

  const int s0  = valid ? offs[n]     : 0;
  const int s1v = valid ? offs[n + 1] : 0;
  const int nE  = s1v - s0;
  const float aldv = valid ? ald1[n*4 + head] : 0.f;

  const ushort_t* hcol = h1b + s*64 + l8*8;
  float acc[8] = {0.f,0.f,0.f,0.f,0.f,0.f,0.f,0.f};
  float dsum = 0.f;

  const int nC = (nE + 7) >> 3;
  for (int c = 0; c < nC; ++c){
    const int idx = s0 + c*8 + l8;
    int sc = 0; float a = 0.f;
    if (idx < s1v){
      sc = ssrc[idx];
      a  = __expf(lrelu(als[sc*4 + head] + aldv));
    }
    shsrc[wave][g][l8] = sc;
    shal[wave][g][l8]  = a;
    dsum += a;                             // each lane sums the alphas IT staged
    #pragma unroll
    for (int k = 0; k < 8; ++k){
      const int scb  = shsrc[wave][g][k];
      const float al = shal[wave][g][k];
      const uint4 v = *(const uint4*)(hcol + ((size_t)scb << 9));
      FMA8(v, al);
    }
  }

  // 3-shuffle within-group denominator reduce (group = aligned 8 lanes)
  dsum += __shfl_xor(dsum, 1);
  dsum += __shfl_xor(dsum, 2);
  dsum += __shfl_xor(dsum, 4);

  if (valid){
    const float rd = 1.0f / (dsum + 1e-16f);
    const float4 ba = *(const float4*)(b1 + s*64 + l8*8);
    const float4 bb = *(const float4*)(b1 + s*64 + l8*8 + 4);
    float o0 = elu(fmaf(acc[0], rd, ba.x)), o1 = elu(fmaf(acc[1], rd, ba.y));
    float o2 = elu(fmaf(acc[2], rd, ba.z)), o3 = elu(fmaf(acc[3], rd, ba.w));
    float o4 = elu(fmaf(acc[4], rd, bb.x)), o5 = elu(fmaf(acc[5], rd, bb.y));
    float o6 = elu(fmaf(acc[6], rd, bb.z)), o7 = elu(fmaf(acc[7], rd, bb.w));
    uint4 o;
    o.x = (uint_t)f2b(o0) | ((uint_t)f2b(o1) << 16);
    o.y = (uint_t)f2b(o2) | ((uint_t)f2b(o3) << 16);
    o.z = (uint_t)f2b(o4) | ((uint_t)f2b(o5) << 16);
    o.w = (uint_t)f2b(o6) | ((uint_t)f2b(o7) << 16);
    *(uint4*)(hb + (size_t)n*F1 + s*64 + l8*8) = o;
  }
}

// ---------------- layer-2 logits from bf16 g ----------------
__global__ __launch_bounds__(64) void logits2_kernel(const ushort_t* __restrict__ gb,
                                                     const float* __restrict__ a_src,
                                                     const float* __restrict__ a_dst,
                                                     float* __restrict__ als,
                                                     float* __restrict__ ald){
  const int n = blockIdx.x;
  const int tid = threadIdx.x;
  const float v = b2f(gb[(size_t)n*F_OUT + tid]);
  float ds = v * a_src[tid];
  float dd = v * a_dst[tid];
  #pragma unroll
  for (int off = 32; off >= 1; off >>= 1){
    ds += __shfl_xor(ds, off);
    dd += __shfl_xor(dd, off);
  }
  if (tid == 0){ als[n] = ds; ald[n] = dd; }
}

// ---------------- layer-2 aggregation (wave per dst) ----------------
__global__ __launch_bounds__(256) void agg2_kernel(const ushort_t* __restrict__ gb,
                                                   const float* __restrict__ als,
                                                   const float* __restrict__ ald2,
                                                   const float* __restrict__ b2,
                                                   const int* __restrict__ offs,
                                                   const int* __restrict__ ssrc,
                                                   float* __restrict__ out){
  __shared__ int   shsrc[4][64];
  __shared__ float shal[4][64];
  const int wave = threadIdx.x >> 6, lane = threadIdx.x & 63;
  const int n = blockIdx.x*4 + wave;
  const float ald = ald2[n];
  const int s0 = offs[n], s1 = offs[n+1];
  const int nE = s1 - s0;

  if (nE <= 64){
    float av = 0.f; int sc = 0;
    if (lane < nE){
      sc = ssrc[s0 + lane];
      av = __expf(lrelu(als[sc] + ald));
    }
    shsrc[wave][lane] = sc;
    shal[wave][lane] = av;

    const ushort_t* gbase = gb + lane;
    const int nE4 = (nE + 3) & ~3;
    float acc = 0.f, dsum = 0.f;

    ushort_t v0 = gbase[(size_t)shsrc[wave][0] << 6];
    ushort_t v1 = gbase[(size_t)shsrc[wave][1] << 6];
    ushort_t v2 = gbase[(size_t)shsrc[wave][2] << 6];
    ushort_t v3 = gbase[(size_t)shsrc[wave][3] << 6];
    float al0 = shal[wave][0];
    float al1 = shal[wave][1];
    float al2 = shal[wave][2];
    float al3 = shal[wave][3];
    for (int k = 0; k < nE4; k += 4){
      ushort_t p0 = v0, p1 = v1, p2 = v2, p3 = v3;
      float q0 = 0.f, q1 = 0.f, q2 = 0.f, q3 = 0.f;
      if (k + 4 < nE4){
        p0 = gbase[(size_t)shsrc[wave][k+4] << 6];
        p1 = gbase[(size_t)shsrc[wave][k+5] << 6];
        p2 = gbase[(size_t)shsrc[wave][k+6] << 6];
        p3 = gbase[(size_t)shsrc[wave][k+7] << 6];
        q0 = shal[wave][k+4];
        q1 = shal[wave][k+5];
        q2 = shal[wave][k+6];
        q3 = shal[wave][k+7];
      }
      dsum += (al0 + al1) + (al2 + al3);
      acc = fmaf(b2f(v0), al0, acc);
      acc = fmaf(b2f(v1), al1, acc);
      acc = fmaf(b2f(v2), al2, acc);
      acc = fmaf(b2f(v3), al3, acc);
      v0 = p0; v1 = p1; v2 = p2; v3 = p3;
      al0 = q0; al1 = q1; al2 = q2; al3 = q3;
    }
    const float rd = 1.0f / (dsum + 1e-16f);
    out[(size_t)n*F_OUT + lane] = fmaf(acc, rd, b2[lane]);
    return;
  }

  // ---- fallback (deg > 64): original two-pass path ----
  float dsum = 0.f;
  for (int e = s0 + lane; e < s1; e += 64)
    dsum += __expf(lrelu(als[ssrc[e]] + ald));
  #pragma unroll
  for (int off = 32; off >= 1; off >>= 1)
    dsum += __shfl_xor(dsum, off);
  const float rd = 1.0f / (dsum + 1e-16f);

  float acc = 0.f;
  for (int ce = s0; ce < s1; ce += 64){
    const int idx = ce + lane;
    if (idx < s1){
      const int sc = ssrc[idx];
      shsrc[wave][lane] = sc;
      shal[wave][lane] = __expf(lrelu(als[sc] + ald)) * rd;
    }
    const int nB = min(64, s1 - ce);
    for (int k = 0; k < nB; ++k){
      const int scb = shsrc[wave][k];
      const float al = shal[wave][k];
      acc = fmaf(b2f(gb[(size_t)scb*F_OUT + lane]), al, acc);
    }
  }
  out[(size_t)n*F_OUT + lane] = acc + b2[lane];
}

#undef FMA8

extern "C" void kernel_launch(void* const* d_in, const int* in_sizes, int n_in,
                              void* d_out, int out_size, void* d_ws, size_t ws_size,
                              hipStream_t stream){
  const float* x      = (const float*)d_in[0];
  const int*   ei     = (const int*)  d_in[1];
  const float* W1     = (const float*)d_in[2];
  const float* a_src1 = (const float*)d_in[3];
  const float* a_dst1 = (const float*)d_in[4];
  const float* b1     = (const float*)d_in[5];
  const float* W2     = (const float*)d_in[6];
  const float* a_src2 = (const float*)d_in[7];
  const float* a_dst2 = (const float*)d_in[8];
  const float* b2     = (const float*)d_in[9];
  float* out = (float*)d_out;

  char* ws = (char*)d_ws;
  ushort_t* h1b  = (ushort_t*)(ws + 0UL);            // [N,512] bf16 = 51.2 MB
  ushort_t* hb   = (ushort_t*)(ws + 51200000UL);     // [N,512] bf16 = 51.2 MB
  ushort_t* xb   = (ushort_t*)(ws + 102400000UL);    // [N,256] bf16 = 25.6 MB
  ushort_t* gb   = (ushort_t*)(ws + 128000000UL);    // [N,64]  bf16 = 6.4 MB
  ushort_t* W1t  = (ushort_t*)(ws + 134400000UL);    // [512][256] bf16
  ushort_t* W2t  = (ushort_t*)(ws + 134662144UL);    // [64][512] bf16
  float*    als1 = (float*)   (ws + 134727680UL);    // [N,4]
  float*    ald1 = (float*)   (ws + 135527680UL);    // [N,4]
  float*    als2 = (float*)   (ws + 136327680UL);    // [N]  (aliases perm; logits2 runs after agg1s)
  float*    ald2 = (float*)   (ws + 136527680UL);    // [N]
  int*      deg  = (int*)     (ws + 136727680UL);    // [N]
  int*      offs = (int*)     (ws + 136927680UL);    // [N+1]
  int*      bsum = (int*)     (ws + 137127744UL);    // [196]
  int*      bbase= (int*)     (ws + 137128544UL);    // [196]
  int*      cur  = (int*)     (ws + 137129600UL);    // [N]
  int*      ssrc = (int*)     (ws + 137329600UL);    // [E_TOT] = 3.4 MB

  // degree-sort scratch: perm aliases als2 (dead until logits2);
  // dhist/dcur alias bsum/bbase (dead after scan3)
  int*      perm  = (int*)    (ws + 136327680UL);    // [N]
  int*      dhist = (int*)    (ws + 137127744UL);    // [128]
  int*      dcur  = (int*)    (ws + 137128544UL);    // [128]

  hipMemsetAsync(deg, 0, 200000, stream);

  const int eb = (E_TOT + 255) / 256;
  const int nb = (N_NODES + 255) / 256;              // 196
  hist_kernel   <<<eb, 256, 0, stream>>>(ei, deg);
  scan1_kernel  <<<nb, 256, 0, stream>>>(deg, offs, bsum);
  scan2_kernel  <<<1, 256, 0, stream>>>(bsum, bbase, nb);
  scan3_kernel  <<<nb, 256, 0, stream>>>(offs, bbase, cur);
  scatter_kernel<<<eb, 256, 0, stream>>>(ei, cur, ssrc);

  // degree-bucket counting sort (after scans: bsum/bbase now dead)
  hipMemsetAsync(dhist, 0, 512, stream);
  dhist_kernel   <<<nb, 256, 0, stream>>>(deg, dhist);
  dscan_kernel   <<<1, 128, 0, stream>>>(dhist, dcur);
  dscatter_kernel<<<nb, 256, 0, stream>>>(deg, dcur, perm);

  cvt_x_kernel        <<<6250, 256, 0, stream>>>(x, xb);
  transpose_bf16_kernel<<<dim3(4, 8), 256, 0, stream>>>(W1, W1t, F_IN, F1);
  transpose_bf16_kernel<<<dim3(8, 1), 256, 0, stream>>>(W2, W2t, F1, F_OUT);

  gemm_bf16<F_IN, 2, 2><<<dim3(391, 4), 256, 0, stream>>>(xb, W1t, h1b, N_NODES, F1);
  logits1_kernel<<<N_NODES, 128, 0, stream>>>(h1b, a_src1, a_dst1, als1, ald1);
  // 1563 dst-blocks (32 dsts each) x 8 feature slices; slice = blockIdx & 7
  agg1s_kernel  <<<12504, 256, 0, stream>>>(h1b, als1, ald1, b1, offs, ssrc, perm, hb);

  gemm_bf16<F1, 4, 1><<<dim3(196, 1), 256, 0, stream>>>(hb, W2t, gb, N_NODES, F_OUT);
  logits2_kernel<<<N_NODES, 64, 0, stream>>>(gb, a_src2, a_dst2, als2, ald2);
  agg2_kernel   <<<12500, 256, 0, stream>>>(gb, als2, ald2, b2, offs, ssrc, out);
}

// Round 12
// 441.517 us; speedup vs baseline: 1.6553x; 1.0739x over previous
//
#include <hip/hip_runtime.h>
#include <math.h>

#define N_NODES 50000
#define N_EDGES 800000
#define E_TOT   850000
#define F_IN    256
#define F1      512
#define HID     128
#define HEADS   4
#define F_OUT   64

typedef __attribute__((ext_vector_type(8))) short short8;
typedef __attribute__((ext_vector_type(4))) float f32x4;
typedef unsigned short ushort_t;
typedef unsigned int uint_t;

__device__ __forceinline__ float lrelu(float x){ return x > 0.f ? x : 0.2f*x; }
__device__ __forceinline__ float elu(float x){ return x > 0.f ? x : expm1f(x); }

__device__ __forceinline__ ushort_t f2b(float f){
  uint_t u = __builtin_bit_cast(uint_t, f);
  u += 0x7fffu + ((u >> 16) & 1u);
  return (ushort_t)(u >> 16);
}
__device__ __forceinline__ float blo(uint_t u){ return __builtin_bit_cast(float, u << 16); }
__device__ __forceinline__ float bhi(uint_t u){ return __builtin_bit_cast(float, u & 0xffff0000u); }
__device__ __forceinline__ float b2f(ushort_t s){ return __builtin_bit_cast(float, (uint_t)s << 16); }

// ---------------- CSR build ----------------
__global__ void hist_kernel(const int* __restrict__ ei, int* __restrict__ deg){
  int e = blockIdx.x*blockDim.x + threadIdx.x;
  if (e >= E_TOT) return;
  int dst = (e < N_EDGES) ? ei[N_EDGES + e] : (e - N_EDGES);
  atomicAdd(&deg[dst], 1);
}

__global__ __launch_bounds__(256) void scan1_kernel(const int* __restrict__ deg,
                                                    int* __restrict__ offs,
                                                    int* __restrict__ bsum){
  __shared__ int sd[256];
  const int tid = threadIdx.x;
  const int i = blockIdx.x*256 + tid;
  int v = (i < N_NODES) ? deg[i] : 0;
  sd[tid] = v; __syncthreads();
  #pragma unroll
  for (int off = 1; off < 256; off <<= 1){
    int t = (tid >= off) ? sd[tid - off] : 0;
    __syncthreads();
    sd[tid] += t;
    __syncthreads();
  }
  if (i < N_NODES) offs[i] = sd[tid] - v;   // block-local exclusive
  if (tid == 255) bsum[blockIdx.x] = sd[255];
}

__global__ __launch_bounds__(256) void scan2_kernel(const int* __restrict__ bsum,
                                                    int* __restrict__ bbase, int nb){
  __shared__ int sd[256];
  const int tid = threadIdx.x;
  int v = (tid < nb) ? bsum[tid] : 0;
  sd[tid] = v; __syncthreads();
  #pragma unroll
  for (int off = 1; off < 256; off <<= 1){
    int t = (tid >= off) ? sd[tid - off] : 0;
    __syncthreads();
    sd[tid] += t;
    __syncthreads();
  }
  if (tid < nb) bbase[tid] = sd[tid] - v;
}

__global__ __launch_bounds__(256) void scan3_kernel(int* __restrict__ offs,
                                                    const int* __restrict__ bbase,
                                                    int* __restrict__ cur){
  const int i = blockIdx.x*256 + threadIdx.x;
  if (i < N_NODES){
    int o = offs[i] + bbase[blockIdx.x];
    offs[i] = o;
    cur[i] = o;
  }
  if (blockIdx.x == 0 && threadIdx.x == 0) offs[N_NODES] = E_TOT;
}

__global__ void scatter_kernel(const int* __restrict__ ei, int* __restrict__ cur,
                               int* __restrict__ ssrc){
  int e = blockIdx.x*blockDim.x + threadIdx.x;
  if (e >= E_TOT) return;
  int src, dst;
  if (e < N_EDGES){ src = ei[e]; dst = ei[N_EDGES + e]; }
  else            { src = e - N_EDGES; dst = src; }
  int pos = atomicAdd(&cur[dst], 1);
  ssrc[pos] = src;
}

// ---------------- prep: fp32 -> bf16 ----------------
__global__ __launch_bounds__(256) void cvt_x_kernel(const float* __restrict__ x,
                                                    ushort_t* __restrict__ xb){
  const int t = blockIdx.x*256 + threadIdx.x;     // 8 elems/thread
  const float4 a = ((const float4*)x)[t*2];
  const float4 b = ((const float4*)x)[t*2 + 1];
  uint4 o;
  o.x = (uint_t)f2b(a.x) | ((uint_t)f2b(a.y) << 16);
  o.y = (uint_t)f2b(a.z) | ((uint_t)f2b(a.w) << 16);
  o.z = (uint_t)f2b(b.x) | ((uint_t)f2b(b.y) << 16);
  o.w = (uint_t)f2b(b.z) | ((uint_t)f2b(b.w) << 16);
  ((uint4*)xb)[t] = o;
}

// W [K][N] fp32 -> Wt [N][K] bf16   (K,N multiples of 64)
__global__ __launch_bounds__(256) void transpose_bf16_kernel(const float* __restrict__ W,
                                                             ushort_t* __restrict__ Wt,
                                                             int K, int N){
  __shared__ float tile[64][65];
  const int k0 = blockIdx.x*64, n0 = blockIdx.y*64;
  const int c = threadIdx.x & 63, r4 = threadIdx.x >> 6;
  for (int r = r4; r < 64; r += 4)
    tile[r][c] = W[(size_t)(k0 + r)*N + n0 + c];
  __syncthreads();
  for (int r = r4; r < 64; r += 4)
    Wt[(size_t)(n0 + r)*K + k0 + c] = f2b(tile[c][r]);
}

// ---------------- bf16 MFMA GEMM: C[M,N] = A[M,K] @ Bt[N,K]^T ----------------
template<int K, int WR, int WC>
__global__ __launch_bounds__(256) void gemm_bf16(const ushort_t* __restrict__ A,
                                                 const ushort_t* __restrict__ Bt,
                                                 ushort_t* __restrict__ C,
                                                 int M, int N){
  constexpr int BM = WR*64, BN = WC*64, BKP = 40;  // pad 32->40 (80B rows, 16B aligned)
  __shared__ ushort_t As[BM*BKP];
  __shared__ ushort_t Bs[BN*BKP];
  const int tid = threadIdx.x;
  const int wave = tid >> 6, lane = tid & 63, quad = lane >> 4, l16 = lane & 15;
  const int wm = wave % WR, wn = wave / WR;
  const int m0 = blockIdx.x*BM, n0 = blockIdx.y*BN;
  f32x4 acc[4][4] = {};
  for (int k0 = 0; k0 < K; k0 += 32){
    #pragma unroll
    for (int s = tid; s < BM*4; s += 256){
      int r = s >> 2, c = s & 3;
      int gr = m0 + r; if (gr >= M) gr = M - 1;
      *(uint4*)(As + r*BKP + c*8) = *(const uint4*)(A + (size_t)gr*K + k0 + c*8);
    }
    #pragma unroll
    for (int s = tid; s < BN*4; s += 256){
      int r = s >> 2, c = s & 3;
      *(uint4*)(Bs + r*BKP + c*8) = *(const uint4*)(Bt + (size_t)(n0 + r)*K + k0 + c*8);
    }
    __syncthreads();
    short8 af[4], bfr[4];
    #pragma unroll
    for (int i = 0; i < 4; ++i)
      af[i] = *(const short8*)(As + (wm*64 + i*16 + l16)*BKP + quad*8);
    #pragma unroll
    for (int j = 0; j < 4; ++j)
      bfr[j] = *(const short8*)(Bs + (wn*64 + j*16 + l16)*BKP + quad*8);
    #pragma unroll
    for (int i = 0; i < 4; ++i)
      #pragma unroll
      for (int j = 0; j < 4; ++j)
        acc[i][j] = __builtin_amdgcn_mfma_f32_16x16x32_bf16(af[i], bfr[j], acc[i][j], 0, 0, 0);
    __syncthreads();
  }
  #pragma unroll
  for (int i = 0; i < 4; ++i){
    #pragma unroll
    for (int r = 0; r < 4; ++r){
      int row = m0 + wm*64 + i*16 + quad*4 + r;
      if (row < M){
        #pragma unroll
        for (int j = 0; j < 4; ++j){
          int col = n0 + wn*64 + j*16 + l16;
          C[(size_t)row*N + col] = f2b(acc[i][j][r]);
        }
      }
    }
  }
}

// ---------------- layer-1 logits from bf16 h1 ----------------
__global__ __launch_bounds__(128) void logits1_kernel(const ushort_t* __restrict__ h1b,
                                                      const float* __restrict__ a_src,
                                                      const float* __restrict__ a_dst,
                                                      float* __restrict__ als,
                                                      float* __restrict__ ald){
  const int n = blockIdx.x;
  const int tid = threadIdx.x;
  const int head = tid >> 5, p = tid & 31;
  const uint2 v = *(const uint2*)(h1b + (size_t)n*F1 + tid*4);
  float h0 = blo(v.x), h1 = bhi(v.x), h2 = blo(v.y), h3 = bhi(v.y);
  const float4 as = *(const float4*)(a_src + head*HID + p*4);
  const float4 ad = *(const float4*)(a_dst + head*HID + p*4);
  float ds = h0*as.x + h1*as.y + h2*as.z + h3*as.w;
  float dd = h0*ad.x + h1*ad.y + h2*ad.z + h3*ad.w;
  #pragma unroll
  for (int off = 16; off >= 1; off >>= 1){
    ds += __shfl_down(ds, off, 32);
    dd += __shfl_down(dd, off, 32);
  }
  if (p == 0){ als[n*4 + head] = ds; ald[n*4 + head] = dd; }
}

// ---------------- layer-1 normalized edge attention weights ----------------
// wave per dst: gather als[src], exp, butterfly denom, write NORMALIZED
// alpha[4][E_TOT]. Verified correct in R4/R5 benches. Slices then read alpha
// contiguously -> removes the 8x-redundant random als gather + exp in agg1s.
__global__ __launch_bounds__(256) void alpha1_kernel(const float* __restrict__ als,
                                                     const float* __restrict__ ald1,
                                                     const int* __restrict__ offs,
                                                     const int* __restrict__ ssrc,
                                                     float* __restrict__ alpha){
  const int wave = threadIdx.x >> 6, lane = threadIdx.x & 63;
  const int n = blockIdx.x*4 + wave;
  const float4 ald = ((const float4*)ald1)[n];
  const int s0 = offs[n], s1 = offs[n+1];
  const int nE = s1 - s0;

  if (nE <= 64){
    float e0 = 0.f, e1 = 0.f, e2 = 0.f, e3 = 0.f;
    const int idx = s0 + lane;
    const bool act = lane < nE;
    if (act){
      const int sc = ssrc[idx];
      const float4 as = ((const float4*)als)[sc];
      e0 = __expf(lrelu(as.x + ald.x));
      e1 = __expf(lrelu(as.y + ald.y));
      e2 = __expf(lrelu(as.z + ald.z));
      e3 = __expf(lrelu(as.w + ald.w));
    }
    float d0 = e0, d1 = e1, d2 = e2, d3 = e3;
    #pragma unroll
    for (int off = 32; off >= 1; off >>= 1){
      d0 += __shfl_xor(d0, off);
      d1 += __shfl_xor(d1, off);
      d2 += __shfl_xor(d2, off);
      d3 += __shfl_xor(d3, off);
    }
    if (act){
      alpha[0*E_TOT + idx] = e0 / (d0 + 1e-16f);
      alpha[1*E_TOT + idx] = e1 / (d1 + 1e-16f);
      alpha[2*E_TOT + idx] = e2 / (d2 + 1e-16f);
      alpha[3*E_TOT + idx] = e3 / (d3 + 1e-16f);
    }
    return;
  }

  // fallback: two passes
  float d0 = 0.f, d1 = 0.f, d2 = 0.f, d3 = 0.f;
  for (int e = s0 + lane; e < s1; e += 64){
    const int sc = ssrc[e];
    const float4 as = ((const float4*)als)[sc];
    d0 += __expf(lrelu(as.x + ald.x));
    d1 += __expf(lrelu(as.y + ald.y));
    d2 += __expf(lrelu(as.z + ald.z));
    d3 += __expf(lrelu(as.w + ald.w));
  }
  #pragma unroll
  for (int off = 32; off >= 1; off >>= 1){
    d0 += __shfl_xor(d0, off);
    d1 += __shfl_xor(d1, off);
    d2 += __shfl_xor(d2, off);
    d3 += __shfl_xor(d3, off);
  }
  const float r0 = 1.f/(d0+1e-16f), r1 = 1.f/(d1+1e-16f);
  const float r2 = 1.f/(d2+1e-16f), r3 = 1.f/(d3+1e-16f);
  for (int e = s0 + lane; e < s1; e += 64){
    const int sc = ssrc[e];
    const float4 as = ((const float4*)als)[sc];
    alpha[0*E_TOT + e] = __expf(lrelu(as.x + ald.x)) * r0;
    alpha[1*E_TOT + e] = __expf(lrelu(as.y + ald.y)) * r1;
    alpha[2*E_TOT + e] = __expf(lrelu(as.z + ald.z)) * r2;
    alpha[3*E_TOT + e] = __expf(lrelu(as.w + ald.w)) * r3;
  }
}

#define FMA8(hv, al) do{ \
  acc[0] = fmaf(blo((hv).x), (al), acc[0]); \
  acc[1] = fmaf(bhi((hv).x), (al), acc[1]); \
  acc[2] = fmaf(blo((hv).y), (al), acc[2]); \
  acc[3] = fmaf(bhi((hv).y), (al), acc[3]); \
  acc[4] = fmaf(blo((hv).z), (al), acc[4]); \
  acc[5] = fmaf(bhi((hv).z), (al), acc[5]); \
  acc[6] = fmaf(blo((hv).w), (al), acc[6]); \
  acc[7] = fmaf(bhi((hv).w), (al), acc[7]); }while(0)

// ---------------- layer-1 aggregation: XCD-sliced, 8-lane group per dst ----
// slice s = blockIdx.x & 7 -> XCD s (keeps the 427->241 MB FETCH cut).
// Wave = 8 CONSECUTIVE dsts (R10 lesson: perm destroys locality). Stage is
// two contiguous 4B loads (ssrc + pre-normalized alpha): no exp, no gather,
// no denominator -> ~40% fewer VALU ops per edge-visit than R8.
__global__ __launch_bounds__(256) void agg1s_kernel(const ushort_t* __restrict__ h1b,
                                                    const float* __restrict__ alpha,
                                                    const float* __restrict__ b1,
                                                    const int* __restrict__ offs,
                                                    const int* __restrict__ ssrc,
                                                    ushort_t* __restrict__ hb){
  __shared__ int   shsrc[4][8][8];
  __shared__ float shal[4][8][8];
  const int wave = threadIdx.x >> 6, lane = threadIdx.x & 63;
  const int s = blockIdx.x & 7;            // feature slice == XCD
  const int gblk = blockIdx.x >> 3;        // dst-group block (32 dsts)
  const int head = s >> 1;
  const int g  = lane >> 3;                // group within wave (0..7)
  const int l8 = lane & 7;                 // lane within group
  const int n = gblk*32 + wave*8 + g;
  const bool valid = n < N_NODES;
  const float* aplane = alpha + (size_t)head*E_TOT;

  const int s0  = valid ? offs[n]     : 0;
  const int s1v = valid ? offs[n + 1] : 0;
  const int nE  = s1v - s0;

  const ushort_t* hcol = h1b + s*64 + l8*8;
  float acc[8] = {0.f,0.f,0.f,0.f,0.f,0.f,0.f,0.f};

  const int nC = (nE + 7) >> 3;
  for (int c = 0; c < nC; ++c){
    const int idx = s0 + c*8 + l8;
    int sc = 0; float a = 0.f;
    if (idx < s1v){
      sc = ssrc[idx];
      a  = aplane[idx];
    }
    shsrc[wave][g][l8] = sc;
    shal[wave][g][l8]  = a;
    #pragma unroll
    for (int k = 0; k < 8; ++k){
      const int scb  = shsrc[wave][g][k];
      const float al = shal[wave][g][k];
      const uint4 v = *(const uint4*)(hcol + ((size_t)scb << 9));
      FMA8(v, al);
    }
  }

  if (valid){
    const float4 ba = *(const float4*)(b1 + s*64 + l8*8);
    const float4 bb = *(const float4*)(b1 + s*64 + l8*8 + 4);
    float o0 = elu(acc[0] + ba.x), o1 = elu(acc[1] + ba.y);
    float o2 = elu(acc[2] + ba.z), o3 = elu(acc[3] + ba.w);
    float o4 = elu(acc[4] + bb.x), o5 = elu(acc[5] + bb.y);
    float o6 = elu(acc[6] + bb.z), o7 = elu(acc[7] + bb.w);
    uint4 o;
    o.x = (uint_t)f2b(o0) | ((uint_t)f2b(o1) << 16);
    o.y = (uint_t)f2b(o2) | ((uint_t)f2b(o3) << 16);
    o.z = (uint_t)f2b(o4) | ((uint_t)f2b(o5) << 16);
    o.w = (uint_t)f2b(o6) | ((uint_t)f2b(o7) << 16);
    *(uint4*)(hb + (size_t)n*F1 + s*64 + l8*8) = o;
  }
}

// ---------------- layer-2 logits from bf16 g ----------------
__global__ __launch_bounds__(64) void logits2_kernel(const ushort_t* __restrict__ gb,
                                                     const float* __restrict__ a_src,
                                                     const float* __restrict__ a_dst,
                                                     float* __restrict__ als,
                                                     float* __restrict__ ald){
  const int n = blockIdx.x;
  const int tid = threadIdx.x;
  const float v = b2f(gb[(size_t)n*F_OUT + tid]);
  float ds = v * a_src[tid];
  float dd = v * a_dst[tid];
  #pragma unroll
  for (int off = 32; off >= 1; off >>= 1){
    ds += __shfl_xor(ds, off);
    dd += __shfl_xor(dd, off);
  }
  if (tid == 0){ als[n] = ds; ald[n] = dd; }
}

// ---------------- layer-2 aggregation (wave per dst) ----------------
__global__ __launch_bounds__(256) void agg2_kernel(const ushort_t* __restrict__ gb,
                                                   const float* __restrict__ als,
                                                   const float* __restrict__ ald2,
                                                   const float* __restrict__ b2,
                                                   const int* __restrict__ offs,
                                                   const int* __restrict__ ssrc,
                                                   float* __restrict__ out){
  __shared__ int   shsrc[4][64];
  __shared__ float shal[4][64];
  const int wave = threadIdx.x >> 6, lane = threadIdx.x & 63;
  const int n = blockIdx.x*4 + wave;
  const float ald = ald2[n];
  const int s0 = offs[n], s1 = offs[n+1];
  const int nE = s1 - s0;

  if (nE <= 64){
    float av = 0.f; int sc = 0;
    if (lane < nE){
      sc = ssrc[s0 + lane];
      av = __expf(lrelu(als[sc] + ald));
    }
    shsrc[wave][lane] = sc;
    shal[wave][lane] = av;

    const ushort_t* gbase = gb + lane;
    const int nE4 = (nE + 3) & ~3;
    float acc = 0.f, dsum = 0.f;

    ushort_t v0 = gbase[(size_t)shsrc[wave][0] << 6];
    ushort_t v1 = gbase[(size_t)shsrc[wave][1] << 6];
    ushort_t v2 = gbase[(size_t)shsrc[wave][2] << 6];
    ushort_t v3 = gbase[(size_t)shsrc[wave][3] << 6];
    float al0 = shal[wave][0];
    float al1 = shal[wave][1];
    float al2 = shal[wave][2];
    float al3 = shal[wave][3];
    for (int k = 0; k < nE4; k += 4){
      ushort_t p0 = v0, p1 = v1, p2 = v2, p3 = v3;
      float q0 = 0.f, q1 = 0.f, q2 = 0.f, q3 = 0.f;
      if (k + 4 < nE4){
        p0 = gbase[(size_t)shsrc[wave][k+4] << 6];
        p1 = gbase[(size_t)shsrc[wave][k+5] << 6];
        p2 = gbase[(size_t)shsrc[wave][k+6] << 6];
        p3 = gbase[(size_t)shsrc[wave][k+7] << 6];
        q0 = shal[wave][k+4];
        q1 = shal[wave][k+5];
        q2 = shal[wave][k+6];
        q3 = shal[wave][k+7];
      }
      dsum += (al0 + al1) + (al2 + al3);
      acc = fmaf(b2f(v0), al0, acc);
      acc = fmaf(b2f(v1), al1, acc);
      acc = fmaf(b2f(v2), al2, acc);
      acc = fmaf(b2f(v3), al3, acc);
      v0 = p0; v1 = p1; v2 = p2; v3 = p3;
      al0 = q0; al1 = q1; al2 = q2; al3 = q3;
    }
    const float rd = 1.0f / (dsum + 1e-16f);
    out[(size_t)n*F_OUT + lane] = fmaf(acc, rd, b2[lane]);
    return;
  }

  // ---- fallback (deg > 64): original two-pass path ----
  float dsum = 0.f;
  for (int e = s0 + lane; e < s1; e += 64)
    dsum += __expf(lrelu(als[ssrc[e]] + ald));
  #pragma unroll
  for (int off = 32; off >= 1; off >>= 1)
    dsum += __shfl_xor(dsum, off);
  const float rd = 1.0f / (dsum + 1e-16f);

  float acc = 0.f;
  for (int ce = s0; ce < s1; ce += 64){
    const int idx = ce + lane;
    if (idx < s1){
      const int sc = ssrc[idx];
      shsrc[wave][lane] = sc;
      shal[wave][lane] = __expf(lrelu(als[sc] + ald)) * rd;
    }
    const int nB = min(64, s1 - ce);
    for (int k = 0; k < nB; ++k){
      const int scb = shsrc[wave][k];
      const float al = shal[wave][k];
      acc = fmaf(b2f(gb[(size_t)scb*F_OUT + lane]), al, acc);
    }
  }
  out[(size_t)n*F_OUT + lane] = acc + b2[lane];
}

#undef FMA8

extern "C" void kernel_launch(void* const* d_in, const int* in_sizes, int n_in,
                              void* d_out, int out_size, void* d_ws, size_t ws_size,
                              hipStream_t stream){
  const float* x      = (const float*)d_in[0];
  const int*   ei     = (const int*)  d_in[1];
  const float* W1     = (const float*)d_in[2];
  const float* a_src1 = (const float*)d_in[3];
  const float* a_dst1 = (const float*)d_in[4];
  const float* b1     = (const float*)d_in[5];
  const float* W2     = (const float*)d_in[6];
  const float* a_src2 = (const float*)d_in[7];
  const float* a_dst2 = (const float*)d_in[8];
  const float* b2     = (const float*)d_in[9];
  float* out = (float*)d_out;

  char* ws = (char*)d_ws;
  ushort_t* h1b  = (ushort_t*)(ws + 0UL);            // [N,512] bf16 = 51.2 MB
  ushort_t* hb   = (ushort_t*)(ws + 51200000UL);     // [N,512] bf16 = 51.2 MB
  ushort_t* xb   = (ushort_t*)(ws + 102400000UL);    // [N,256] bf16 = 25.6 MB
  ushort_t* gb   = (ushort_t*)(ws + 128000000UL);    // [N,64]  bf16 = 6.4 MB
  ushort_t* W1t  = (ushort_t*)(ws + 134400000UL);    // [512][256] bf16
  ushort_t* W2t  = (ushort_t*)(ws + 134662144UL);    // [64][512] bf16
  float*    als1 = (float*)   (ws + 134727680UL);    // [N,4]
  float*    ald1 = (float*)   (ws + 135527680UL);    // [N,4]
  float*    als2 = (float*)   (ws + 136327680UL);    // [N]
  float*    ald2 = (float*)   (ws + 136527680UL);    // [N]
  int*      deg  = (int*)     (ws + 136727680UL);    // [N]
  int*      offs = (int*)     (ws + 136927680UL);    // [N+1]
  int*      bsum = (int*)     (ws + 137127744UL);    // [196]
  int*      bbase= (int*)     (ws + 137128544UL);    // [196]
  int*      cur  = (int*)     (ws + 137129600UL);    // [N]
  int*      ssrc = (int*)     (ws + 137329600UL);    // [E_TOT] = 3.4 MB

  // normalized edge attention [4][E_TOT] fp32 = 13.6 MB, aliased into xb's
  // region — xb is dead after gemm1; alpha1 runs after logits1 (post-gemm1)
  float*    alpha = (float*)  (ws + 102400000UL);

  hipMemsetAsync(deg, 0, 200000, stream);

  const int eb = (E_TOT + 255) / 256;
  const int nb = (N_NODES + 255) / 256;              // 196
  hist_kernel   <<<eb, 256, 0, stream>>>(ei, deg);
  scan1_kernel  <<<nb, 256, 0, stream>>>(deg, offs, bsum);
  scan2_kernel  <<<1, 256, 0, stream>>>(bsum, bbase, nb);
  scan3_kernel  <<<nb, 256, 0, stream>>>(offs, bbase, cur);
  scatter_kernel<<<eb, 256, 0, stream>>>(ei, cur, ssrc);

  cvt_x_kernel        <<<6250, 256, 0, stream>>>(x, xb);
  transpose_bf16_kernel<<<dim3(4, 8), 256, 0, stream>>>(W1, W1t, F_IN, F1);
  transpose_bf16_kernel<<<dim3(8, 1), 256, 0, stream>>>(W2, W2t, F1, F_OUT);

  gemm_bf16<F_IN, 2, 2><<<dim3(391, 4), 256, 0, stream>>>(xb, W1t, h1b, N_NODES, F1);
  logits1_kernel<<<N_NODES, 128, 0, stream>>>(h1b, a_src1, a_dst1, als1, ald1);
  alpha1_kernel <<<12500, 256, 0, stream>>>(als1, ald1, offs, ssrc, alpha);
  // 1563 dst-blocks (32 consecutive dsts each) x 8 slices; slice = blockIdx & 7
  agg1s_kernel  <<<12504, 256, 0, stream>>>(h1b, alpha, b1, offs, ssrc, hb);

  gemm_bf16<F1, 4, 1><<<dim3(196, 1), 256, 0, stream>>>(hb, W2t, gb, N_NODES, F_OUT);
  logits2_kernel<<<N_NODES, 64, 0, stream>>>(gb, a_src2, a_dst2, als2, ald2);
  agg2_kernel   <<<12500, 256, 0, stream>>>(gb, als2, ald2, b2, offs, ssrc, out);
}